// Round 2
// baseline (231.607 us; speedup 1.0000x reference)
//
#include <hip/hip_runtime.h>
#include <hip/hip_bf16.h>
#include <stdint.h>

// Conv2d: x[128][256][256] (f32), w[256][128][3][3] (f32), bias[256] (f32)
// out[256][256][256] (f32).  pad=1, stride=1.
// Strategy: bf16 MFMA implicit GEMM. M=COUT=256, N=65536 pixels, K=128ch x 9 taps.
//   ws layout: x_p bf16 [258][258][128] (padded, channel-innermost) = 17,040,384 B
//              W_pk bf16 [9][256][128]                              =    589,824 B
// R4 changes (R3 post-mortem: 84+64=148 regs -> pow2 HW quantum 256 -> 2 waves/SIMD
// = 23.7% occupancy cliff; __syncthreads() vmcnt(0)-drains the "async" stage anyway):
//   1. NO LDS AT ALL. B-fragments read directly from xp global: channel-innermost
//      layout makes every (kh,kw) tap a 16B-aligned load. Per-block x slice
//      (~100 KB) + weights (0.6 MB) are L2-resident (guide m169: LDS-staging
//      L2-fit data is pure overhead). Removes both barriers/iter (the convoy),
//      all staging VALU, all inter-thread deps.
//   2. __launch_bounds__(256, 4) pins total regs <= 128 (with 64 acc AGPRs ->
//      VGPR side <= 64) so the 128-reg occupancy cliff cannot recur.
//      16 waves/CU; 4 waves/SIMD hide each other's L2 latency; no convoy.
//   3. Keep bijective XCD swizzle — now load-bearing: confines each XCD's
//      concurrent blocks to a 64-row xp band (~4.4 MB ~ its private L2).
// Accumulation order identical to R2/R3 -> bit-identical output expected.

#define CIN   128
#define COUT  256
#define HH    256
#define WW    256
#define HP    258
#define WP    258
#define XP_ELEMS (HP * WP * CIN)   // 8,520,192 bf16 elements

typedef __attribute__((ext_vector_type(8))) __bf16 bf16x8;
typedef __attribute__((ext_vector_type(4))) float  floatx4;
typedef __attribute__((ext_vector_type(8))) short  short8;

// ---------------- prep 1: zero the padded border of x_p ----------------
__global__ void zero_border(unsigned short* __restrict__ xp) {
    int p  = blockIdx.x;          // 0..1027 border pixels
    int ch = threadIdx.x;         // 0..127
    int hp, wp;
    if (p < 258)      { hp = 0;   wp = p; }
    else if (p < 516) { hp = 257; wp = p - 258; }
    else { int s = p - 516; hp = 1 + (s >> 1); wp = (s & 1) * 257; }
    xp[(hp * WP + wp) * CIN + ch] = 0;
}

// ---------------- prep 2: transpose+cast x[c][h][w] -> x_p[h+1][w+1][c] ----------------
__global__ __launch_bounds__(256) void xpose_pad(const float* __restrict__ x,
                                                 unsigned short* __restrict__ xp) {
    __shared__ __align__(16) unsigned short tile[64][136];  // pad 128->136 (16B-aligned rows)
    int h  = blockIdx.x;            // 0..255
    int w0 = blockIdx.y << 6;       // 0,64,128,192
    int t  = threadIdx.x;
    int wl  = t & 63;               // 0..63
    int icq = t >> 6;               // 0..3
    const float* src = x + h * WW + w0 + wl;
#pragma unroll
    for (int icb = 0; icb < 32; ++icb) {
        int ic = icb * 4 + icq;
        __hip_bfloat16 b = __float2bfloat16(src[ic * (HH * WW)]);
        tile[wl][ic] = __builtin_bit_cast(unsigned short, b);
    }
    __syncthreads();
    int wl2 = t >> 2, q = t & 3;    // 64 rows x 4 chunks of 64B
    const short8* s8 = (const short8*)&tile[wl2][q * 32];
    short8* d8 = (short8*)(xp + ((size_t)(h + 1) * WP + (w0 + 1) + wl2) * CIN + q * 32);
#pragma unroll
    for (int i = 0; i < 4; ++i) d8[i] = s8[i];
}

// ---------------- prep 3: pack weights -> bf16 W_pk[kk][o][ic] ----------------
__global__ __launch_bounds__(256) void wpack(const float* __restrict__ w,
                                             unsigned short* __restrict__ wp) {
    int idx = blockIdx.x * 256 + threadIdx.x;   // 0..294911
    int kk  = idx >> 15;                        // / (256*128)
    int rem = idx & 32767;                      // o*128 + ic
    __hip_bfloat16 b = __float2bfloat16(w[rem * 9 + kk]);
    wp[idx] = __builtin_bit_cast(unsigned short, b);
}

// ---------------- main: 128x128 output tile, 4 waves, 16x16x32 bf16 MFMA ----------------
// No LDS, no barriers. Each wave streams A (weights) and B (xp pixels) straight
// from global through L1/L2 into MFMA fragments. Waves 0,2 / 1,3 share B;
// waves 0,1 / 2,3 share A -> L1 dedup within the CU.
__global__ __launch_bounds__(256, 4) void conv_mfma(
    const unsigned short* __restrict__ xp,   // [258][258][128] bf16
    const unsigned short* __restrict__ wpk,  // [9][256][128]   bf16
    const float* __restrict__ bias,          // [256] f32
    float* __restrict__ out) {               // [256][65536] f32
    const int tid  = threadIdx.x;
    const int lane = tid & 63;
    const int wv   = tid >> 6;          // 0..3
    const int l15  = lane & 15;
    const int lg   = lane >> 4;         // 0..3

    // XCD-aware bijective swizzle: grid = 1024 blocks = 8 XCDs x 128.
    // XCD k gets a contiguous swz band -> one m-half x 64-row xp window
    // (~4.4 MB) stays resident in that XCD's private L2.
    const int orig = blockIdx.x + (blockIdx.y << 9);        // gridDim.x = 512
    const int swz  = ((orig & 7) << 7) + (orig >> 3);       // bijective (1024 % 8 == 0)
    const int m0 = (swz >> 9) << 7;
    const int h  = (swz & 511) >> 1;
    const int w0 = (swz & 1) << 7;

    const int wave_m = (wv >> 1) << 6;  // 0 or 64
    const int wave_n = (wv & 1) << 6;   // 0 or 64

    floatx4 acc[4][4];
#pragma unroll
    for (int fi = 0; fi < 4; ++fi)
#pragma unroll
        for (int fj = 0; fj < 4; ++fj) {
            floatx4 z = {0.f, 0.f, 0.f, 0.f};
            acc[fi][fj] = z;
        }

    // A base: weight row (m0+wave_m+l15), k-octet lg.  +kk*COUT*CIN, +fi*16*CIN, +t*32.
    const unsigned short* wb = wpk + (size_t)(m0 + wave_m + l15) * CIN + lg * 8;
    // B base: pixel (h, w0+wave_n+l15), k-octet lg.    +(kh*WP+kw)*CIN, +fj*16*CIN, +t*32.
    const unsigned short* xb = xp + ((size_t)h * WP + w0 + wave_n + l15) * CIN + lg * 8;

    for (int t = 0; t < 4; ++t) {              // K-slice: channels [t*32, t*32+32)
        const int ic0 = t << 5;
#pragma unroll
        for (int kh = 0; kh < 3; ++kh) {
#pragma unroll
            for (int kw = 0; kw < 3; ++kw) {
                const int kk = kh * 3 + kw;
                bf16x8 a[4], b[4];
#pragma unroll
                for (int fi = 0; fi < 4; ++fi)
                    a[fi] = *(const bf16x8*)(wb + (size_t)kk * (COUT * CIN) + fi * 16 * CIN + ic0);
#pragma unroll
                for (int fj = 0; fj < 4; ++fj)
                    b[fj] = *(const bf16x8*)(xb + ((size_t)kh * WP + kw + fj * 16) * CIN + ic0);
#pragma unroll
                for (int fi = 0; fi < 4; ++fi)
#pragma unroll
                    for (int fj = 0; fj < 4; ++fj)
                        acc[fi][fj] = __builtin_amdgcn_mfma_f32_16x16x32_bf16(
                            a[fi], b[fj], acc[fi][fj], 0, 0, 0);
            }
        }
    }

    // epilogue: D row=(lane>>4)*4+reg, col=lane&15 ; add bias, store f32
    const int nbase = h * WW + w0 + wave_n + l15;
#pragma unroll
    for (int fi = 0; fi < 4; ++fi) {
        int mrow = m0 + wave_m + fi * 16 + lg * 4;
#pragma unroll
        for (int r = 0; r < 4; ++r) {
            float bv = bias[mrow + r];
#pragma unroll
            for (int fj = 0; fj < 4; ++fj)
                out[(size_t)(mrow + r) * (HH * WW) + nbase + fj * 16] = acc[fi][fj][r] + bv;
        }
    }
}

extern "C" void kernel_launch(void* const* d_in, const int* in_sizes, int n_in,
                              void* d_out, int out_size, void* d_ws, size_t ws_size,
                              hipStream_t stream) {
    (void)in_sizes; (void)n_in; (void)out_size; (void)ws_size;
    const float* x    = (const float*)d_in[0];   // 128*256*256
    const float* w    = (const float*)d_in[1];   // 256*128*3*3
    const float* bias = (const float*)d_in[2];   // 256
    float* out = (float*)d_out;

    unsigned short* xp  = (unsigned short*)d_ws;            // bf16 [258][258][128]
    unsigned short* wpk = xp + XP_ELEMS;                    // bf16 [9][256][128]

    zero_border<<<dim3(1028), dim3(128), 0, stream>>>(xp);
    xpose_pad<<<dim3(256, 4), dim3(256), 0, stream>>>(x, xp);
    wpack<<<dim3(1152), dim3(256), 0, stream>>>(w, wpk);
    conv_mfma<<<dim3(512, 2), dim3(256), 0, stream>>>(xp, wpk, bias, out);
}

// Round 3
// 154.792 us; speedup vs baseline: 1.4962x; 1.4962x over previous
//
#include <hip/hip_runtime.h>
#include <hip/hip_bf16.h>
#include <stdint.h>

// Conv2d: x[128][256][256] (f32), w[256][128][3][3] (f32), bias[256] (f32)
// out[256][256][256] (f32).  pad=1, stride=1.
// bf16 MFMA implicit GEMM: M=COUT=256, N=65536 pixels, K=9 taps x 128 ch = 1152.
//   ws: x_p bf16 [258][258][128] (padded, channel-innermost), W_pk bf16 [9][256][128].
//
// R5 (post-mortem R2-R4: MFMA-busy ~= 15-18us floor in ALL variants; the other
// ~85% is exposed memory latency from shallow (1-tap) lookahead. Structure, not
// mechanism, was the ceiling):
//   Port of the guide's T3 2-phase prefetch template:
//   - One block per output row h: grid=256 = #CUs, zero tail. 8 waves (512 thr),
//     wave tile 128x64, acc[8][4] = 128 AGPR. K_STEP=32 (one tap x 32ch quarter),
//     36 steps. kw fixed per step -> B-tile = 256 CONTIGUOUS pixels of one padded
//     row (no im2col overlap inside a step).
//   - LDS 64KB static: double-buffered (A 16KB + B 16KB). Plane/chunk layout
//     (chunk = k_oct*256 + row/pix): lane-contiguous global_load_lds dests AND
//     2-way (free) ds_read_b128 — no swizzle needed (R2-proven).
//   - Per step: issue next stage FIRST (4 global_load_lds), then ds_read+MFMA on
//     current buffer (~1240 cyc >= L2/L3 latency), then ONE __syncthreads().
//     The vmcnt(0) drain at the barrier finds the stage already complete.
//   - __launch_bounds__(512,2): cap 256 regs, 2 waves/SIMD, 1 block/CU (the
//     occupancy regime the 256^2 8-phase template proves sufficient).
//   - XCD swizzle: 32 consecutive rows per XCD -> 3-row B reuse is L2-local.

#define CIN   128
#define COUT  256
#define HH    256
#define WW    256
#define HP    258
#define WP    258
#define XP_ELEMS (HP * WP * CIN)   // 8,520,192 bf16 elements

typedef __attribute__((ext_vector_type(8))) __bf16 bf16x8;
typedef __attribute__((ext_vector_type(4))) float  floatx4;
typedef __attribute__((ext_vector_type(8))) short  short8;

// ---------------- prep 1: zero the padded border of x_p ----------------
__global__ void zero_border(unsigned short* __restrict__ xp) {
    int p  = blockIdx.x;          // 0..1027 border pixels
    int ch = threadIdx.x;         // 0..127
    int hp, wp;
    if (p < 258)      { hp = 0;   wp = p; }
    else if (p < 516) { hp = 257; wp = p - 258; }
    else { int s = p - 516; hp = 1 + (s >> 1); wp = (s & 1) * 257; }
    xp[(hp * WP + wp) * CIN + ch] = 0;
}

// ---------------- prep 2: transpose+cast x[c][h][w] -> x_p[h+1][w+1][c] ----------------
__global__ __launch_bounds__(256) void xpose_pad(const float* __restrict__ x,
                                                 unsigned short* __restrict__ xp) {
    __shared__ __align__(16) unsigned short tile[64][136];  // pad 128->136 (16B-aligned rows)
    int h  = blockIdx.x;            // 0..255
    int w0 = blockIdx.y << 6;       // 0,64,128,192
    int t  = threadIdx.x;
    int wl  = t & 63;               // 0..63
    int icq = t >> 6;               // 0..3
    const float* src = x + h * WW + w0 + wl;
#pragma unroll
    for (int icb = 0; icb < 32; ++icb) {
        int ic = icb * 4 + icq;
        __hip_bfloat16 b = __float2bfloat16(src[ic * (HH * WW)]);
        tile[wl][ic] = __builtin_bit_cast(unsigned short, b);
    }
    __syncthreads();
    int wl2 = t >> 2, q = t & 3;    // 64 rows x 4 chunks of 64B
    const short8* s8 = (const short8*)&tile[wl2][q * 32];
    short8* d8 = (short8*)(xp + ((size_t)(h + 1) * WP + (w0 + 1) + wl2) * CIN + q * 32);
#pragma unroll
    for (int i = 0; i < 4; ++i) d8[i] = s8[i];
}

// ---------------- prep 3: pack weights -> bf16 W_pk[kk][o][ic] ----------------
__global__ __launch_bounds__(256) void wpack(const float* __restrict__ w,
                                             unsigned short* __restrict__ wp) {
    int idx = blockIdx.x * 256 + threadIdx.x;   // 0..294911
    int kk  = idx >> 15;                        // / (256*128)
    int rem = idx & 32767;                      // o*128 + ic
    __hip_bfloat16 b = __float2bfloat16(w[rem * 9 + kk]);
    wp[idx] = __builtin_bit_cast(unsigned short, b);
}

// ---------------- main: 256(M) x 256(pixels of row h), 8 waves, 36 K-steps ----------------
// LDS per buffer: A planes [oct 0..3][row 0..255] 16B chunks (8192 shorts),
//                 B planes [oct 0..3][pix 0..255] 16B chunks (8192 shorts).
// a-frag (fi): chunk lg*256 + wave_m+fi*16+l15 ; b-frag (fj): lg*256 + wave_n+fj*16+l15.
// 16-lane groups read 16 consecutive chunks -> 2-way bank use (free).
__global__ __launch_bounds__(512, 2) void conv_mfma(
    const unsigned short* __restrict__ xp,   // [258][258][128] bf16
    const unsigned short* __restrict__ wpk,  // [9][256][128]   bf16
    const float* __restrict__ bias,          // [256] f32
    float* __restrict__ out) {               // [256][65536] f32
    __shared__ __align__(16) unsigned short x_lds[2 * 16384];   // 65,536 B

    const int tid  = threadIdx.x;            // 0..511
    const int lane = tid & 63;
    const int wv   = tid >> 6;               // 0..7
    const int l15  = lane & 15;
    const int lg   = lane >> 4;              // 0..3
    const int wave_m = (wv >> 2) << 7;       // 0 or 128
    const int wave_n = (wv & 3) << 6;        // 0,64,128,192

    // XCD swizzle (bijective, 256 % 8 == 0): XCD k gets rows [k*32, k*32+32).
    const int orig = blockIdx.x;
    const int h    = ((orig & 7) << 5) | (orig >> 3);

    // Per-thread staging source offset (shorts): row/pix = tid&255, oct = tid>>8.
    // Chunk i=0: c=tid (oct 0/1); i=1: c=tid+512 (oct 2/3) -> src +16 shorts,
    // dest +4096 shorts. Dests are lane-contiguous 16B within each wave.
    const int s0 = (tid & 255) * CIN + (tid >> 8) * 8;

    auto stage = [&](int buf, int kh, int kw, int kk, int icq) {
        unsigned short* base = x_lds + buf * 16384;
        const unsigned short* asrc = wpk + (size_t)kk * (COUT * CIN) + icq * 32 + s0;
        const unsigned short* bsrc = xp + ((size_t)(h + kh) * WP + kw) * CIN + icq * 32 + s0;
        __builtin_amdgcn_global_load_lds(
            (const __attribute__((address_space(1))) void*)asrc,
            (__attribute__((address_space(3))) void*)(base + tid * 8), 16, 0, 0);
        __builtin_amdgcn_global_load_lds(
            (const __attribute__((address_space(1))) void*)(asrc + 16),
            (__attribute__((address_space(3))) void*)(base + 4096 + tid * 8), 16, 0, 0);
        __builtin_amdgcn_global_load_lds(
            (const __attribute__((address_space(1))) void*)bsrc,
            (__attribute__((address_space(3))) void*)(base + 8192 + tid * 8), 16, 0, 0);
        __builtin_amdgcn_global_load_lds(
            (const __attribute__((address_space(1))) void*)(bsrc + 16),
            (__attribute__((address_space(3))) void*)(base + 12288 + tid * 8), 16, 0, 0);
    };

    floatx4 acc[8][4];
#pragma unroll
    for (int fi = 0; fi < 8; ++fi)
#pragma unroll
        for (int fj = 0; fj < 4; ++fj) {
            floatx4 z = {0.f, 0.f, 0.f, 0.f};
            acc[fi][fj] = z;
        }

    // Prologue: stage step 0 into buffer 0; barrier drains vmcnt(0).
    stage(0, 0, 0, 0, 0);
    __syncthreads();

    // 36 K-steps, fully unrolled so kh/kw (div-by-3) and stage targets const-fold.
#pragma unroll
    for (int kk = 0; kk < 9; ++kk) {
#pragma unroll
        for (int icq = 0; icq < 4; ++icq) {
            const int t   = kk * 4 + icq;
            const int cur = t & 1;

            // Phase 1: issue next step's stage (flies under this step's MFMA).
            if (t < 35) {
                const int tn  = t + 1;
                const int kkn = tn >> 2, icqn = tn & 3;
                const int khn = kkn / 3, kwn = kkn - khn * 3;
                stage(cur ^ 1, khn, kwn, kkn, icqn);
            }

            // Phase 2: ds_read fragments + MFMA on current buffer.
            const unsigned short* Ab = x_lds + cur * 16384;
            const unsigned short* Bb = Ab + 8192;
            bf16x8 a[8], b[4];
#pragma unroll
            for (int fj = 0; fj < 4; ++fj)
                b[fj] = *(const bf16x8*)(Bb + (lg * 256 + wave_n + fj * 16 + l15) * 8);
#pragma unroll
            for (int fi = 0; fi < 8; ++fi)
                a[fi] = *(const bf16x8*)(Ab + (lg * 256 + wave_m + fi * 16 + l15) * 8);

            __builtin_amdgcn_s_setprio(1);
#pragma unroll
            for (int fi = 0; fi < 8; ++fi)
#pragma unroll
                for (int fj = 0; fj < 4; ++fj)
                    acc[fi][fj] = __builtin_amdgcn_mfma_f32_16x16x32_bf16(
                        a[fi], b[fj], acc[fi][fj], 0, 0, 0);
            __builtin_amdgcn_s_setprio(0);

            // One barrier per step: drains staged vmcnt + guards buffer reuse.
            __syncthreads();
        }
    }

    // Epilogue: D row = lg*4 + reg (within 16), col = l15; add bias, store f32.
    const int nbase = h * WW + wave_n + l15;
#pragma unroll
    for (int fi = 0; fi < 8; ++fi) {
        int mrow = wave_m + fi * 16 + lg * 4;
#pragma unroll
        for (int r = 0; r < 4; ++r) {
            float bv = bias[mrow + r];
#pragma unroll
            for (int fj = 0; fj < 4; ++fj)
                out[(size_t)(mrow + r) * (HH * WW) + nbase + fj * 16] = acc[fi][fj][r] + bv;
        }
    }
}

extern "C" void kernel_launch(void* const* d_in, const int* in_sizes, int n_in,
                              void* d_out, int out_size, void* d_ws, size_t ws_size,
                              hipStream_t stream) {
    (void)in_sizes; (void)n_in; (void)out_size; (void)ws_size;
    const float* x    = (const float*)d_in[0];   // 128*256*256
    const float* w    = (const float*)d_in[1];   // 256*128*3*3
    const float* bias = (const float*)d_in[2];   // 256
    float* out = (float*)d_out;

    unsigned short* xp  = (unsigned short*)d_ws;            // bf16 [258][258][128]
    unsigned short* wpk = xp + XP_ELEMS;                    // bf16 [9][256][128]

    zero_border<<<dim3(1028), dim3(128), 0, stream>>>(xp);
    xpose_pad<<<dim3(256, 4), dim3(256), 0, stream>>>(x, xp);
    wpack<<<dim3(1152), dim3(256), 0, stream>>>(w, wpk);
    conv_mfma<<<dim3(256), dim3(512), 0, stream>>>(xp, wpk, bias, out);
}

// Round 4
// 131.917 us; speedup vs baseline: 1.7557x; 1.1734x over previous
//
#include <hip/hip_runtime.h>
#include <hip/hip_bf16.h>
#include <stdint.h>

// Conv2d: x[128][256][256] (f32), w[256][128][3][3] (f32), bias[256] (f32)
// out[256][256][256] (f32).  pad=1, stride=1.
// bf16 MFMA implicit GEMM: M=COUT=256, N=65536 pixels, K=9 taps x 128 ch = 1152.
//   ws: x_p bf16 [258][258][128] (padded, channel-innermost), W_pk bf16 [9][256][128].
//
// R6 (post-mortem R5: per-step 4530 cyc vs 1242 MFMA need; staging lanes strode
// 256 B -> each global_load_lds touched 64 lines using 16 B of each = 2048 L1
// line-requests/step/CU. L1 REQUEST RATE was the bottleneck all along):
//   - K_STEP=64 (tap x channel-half), 18 steps. LDS row-major [256 rows][64ch]
//     per tile (A=weights rows, B=pixels). Staging lanes now walk consecutive
//     16 B octets within each row's 128 B half: 16 lines/instr = fully
//     request-efficient (4x fewer requests/byte than R5).
//   - Row-major stride-128B would be a 16-way ds_read_b128 conflict (G4), so
//     XOR-swizzle (rule #21, both-sides-or-neither): physical oct = logical
//     oct ^ (row&7). Linear LDS dest + pre-swizzled global SOURCE (permutation
//     stays inside each 128 B run -> coalescing intact) + swizzled ds_read
//     (each 8-lane service phase hits 8 distinct bank-quads -> conflict-free).
//   - LDS 2 x (32K A + 32K B) = 131072 B, 1 block/CU, 8 waves, same proven
//     2-phase schedule: stage(next) -> compute(cur) -> one barrier.
//   - Preps fused into ONE kernel (4 launches -> 2); border-zero vectorized.
// FP accumulation order identical to R5 -> bit-identical output expected.

#define CIN   128
#define COUT  256
#define HH    256
#define WW    256
#define HP    258
#define WP    258
#define XP_ELEMS (HP * WP * CIN)   // 8,520,192 bf16 elements

typedef __attribute__((ext_vector_type(8))) __bf16 bf16x8;
typedef __attribute__((ext_vector_type(4))) float  floatx4;
typedef __attribute__((ext_vector_type(8))) short  short8;

#define AS1 __attribute__((address_space(1)))
#define AS3 __attribute__((address_space(3)))

// ---------------- fused prep: xpose_pad | wpack | zero_border ----------------
__global__ __launch_bounds__(256) void prep(const float* __restrict__ x,
                                            const float* __restrict__ w,
                                            unsigned short* __restrict__ xp,
                                            unsigned short* __restrict__ wpk) {
    __shared__ __align__(16) unsigned short tile[64][136];  // xpose region only
    const int bid = blockIdx.x;
    const int t   = threadIdx.x;
    if (bid < 1024) {
        // transpose+cast x[c][h][w] -> x_p[h+1][w+1][c]
        int h  = bid >> 2;
        int w0 = (bid & 3) << 6;
        int wl = t & 63, icq = t >> 6;
        const float* src = x + h * WW + w0 + wl;
#pragma unroll
        for (int icb = 0; icb < 32; ++icb) {
            int ic = icb * 4 + icq;
            __hip_bfloat16 b = __float2bfloat16(src[ic * (HH * WW)]);
            tile[wl][ic] = __builtin_bit_cast(unsigned short, b);
        }
        __syncthreads();
        int wl2 = t >> 2, q = t & 3;    // 64 rows x 4 chunks of 64B
        const short8* s8 = (const short8*)&tile[wl2][q * 32];
        short8* d8 = (short8*)(xp + ((size_t)(h + 1) * WP + (w0 + 1) + wl2) * CIN + q * 32);
#pragma unroll
        for (int i = 0; i < 4; ++i) d8[i] = s8[i];
    } else if (bid < 2176) {
        // pack weights -> bf16 W_pk[kk][o][ic]
        int idx = (bid - 1024) * 256 + t;           // 0..294911
        int kk  = idx >> 15;
        int rem = idx & 32767;                      // o*128 + ic
        __hip_bfloat16 b = __float2bfloat16(w[rem * 9 + kk]);
        wpk[idx] = __builtin_bit_cast(unsigned short, b);
    } else {
        // zero the padded border: 1028 px x 16 octets, short8 stores
        int cid = (bid - 2176) * 256 + t;           // 0..16447
        if (cid < 16448) {
            int p = cid >> 4, oct = cid & 15;
            int hp, wp;
            if (p < 258)      { hp = 0;   wp = p; }
            else if (p < 516) { hp = 257; wp = p - 258; }
            else { int s = p - 516; hp = 1 + (s >> 1); wp = (s & 1) * 257; }
            short8 z = {0, 0, 0, 0, 0, 0, 0, 0};
            *(short8*)(xp + ((size_t)hp * WP + wp) * CIN + oct * 8) = z;
        }
    }
}

// ---------------- main: 256(M) x 256(pixels of row h), 8 waves, 18 K-steps ----------------
// Per buffer: A[256 o][64 ch] then B[256 pix][64 ch], 16384 shorts each.
// Swizzle: physical octet p = logical oct ^ (row & 7)  (octet = 8 shorts = 16 B).
//   stage : lane writes LDS chunk c = i*512+tid linearly; fetches global octet
//           (tid&7)^((tid>>3)&7) of row i*64 + (tid>>3)  -- coalesced 128 B runs.
//   read  : frag (row, oct) at byte row*128 + (oct^(row&7))*16.
__global__ __launch_bounds__(512, 2) void conv_mfma(
    const unsigned short* __restrict__ xp,   // [258][258][128] bf16
    const unsigned short* __restrict__ wpk,  // [9][256][128]   bf16
    const float* __restrict__ bias,          // [256] f32
    float* __restrict__ out) {               // [256][65536] f32
    __shared__ __align__(16) unsigned short x_lds[2 * 32768];   // 131,072 B

    const int tid  = threadIdx.x;            // 0..511
    const int lane = tid & 63;
    const int wv   = tid >> 6;               // 0..7
    const int l15  = lane & 15;
    const int lg   = lane >> 4;              // 0..3
    const int wave_m = (wv >> 2) << 7;       // 0 or 128
    const int wave_n = (wv & 3) << 6;        // 0,64,128,192

    // XCD swizzle (bijective, 256 % 8 == 0): XCD k gets rows [k*32, k*32+32).
    const int orig = blockIdx.x;
    const int h    = ((orig & 7) << 5) | (orig >> 3);

    // Staging per-thread constants: row-group tid>>3, fetch-octet permutation.
    const int soff = (tid >> 3) * CIN + ((((tid & 7) ^ ((tid >> 3) & 7))) << 3);

    auto stage = [&](int buf, int kk, int kh, int kw, int hf) {
        unsigned short* base = x_lds + buf * 32768;
        const unsigned short* asrc = wpk + (size_t)kk * (COUT * CIN) + hf * 64 + soff;
        const unsigned short* bsrc = xp + ((size_t)(h + kh) * WP + kw) * CIN + hf * 64 + soff;
#pragma unroll
        for (int i = 0; i < 4; ++i)
            __builtin_amdgcn_global_load_lds(
                (const AS1 void*)(asrc + i * 8192),
                (AS3 void*)(base + i * 4096 + tid * 8), 16, 0, 0);
#pragma unroll
        for (int i = 0; i < 4; ++i)
            __builtin_amdgcn_global_load_lds(
                (const AS1 void*)(bsrc + i * 8192),
                (AS3 void*)(base + 16384 + i * 4096 + tid * 8), 16, 0, 0);
    };

    floatx4 acc[8][4];
#pragma unroll
    for (int fi = 0; fi < 8; ++fi)
#pragma unroll
        for (int fj = 0; fj < 4; ++fj) {
            floatx4 z = {0.f, 0.f, 0.f, 0.f};
            acc[fi][fj] = z;
        }

    // Per-thread swizzled read octet (shorts): ks=1 flips bit2 of octet (^32).
    const int aoct = (lg ^ (l15 & 7)) << 3;

    // Prologue: stage step 0 into buffer 0; barrier drains vmcnt(0).
    stage(0, 0, 0, 0, 0);
    __syncthreads();

#pragma unroll
    for (int t2 = 0; t2 < 18; ++t2) {        // step = (kk, half)
        const int cur = t2 & 1;

        // Phase 1: issue next step's stage (lands under this step's MFMA).
        if (t2 < 17) {
            const int tn  = t2 + 1;
            const int kkn = tn >> 1, hfn = tn & 1;
            const int khn = kkn / 3, kwn = kkn - khn * 3;
            stage(cur ^ 1, kkn, khn, kwn, hfn);
        }

        // Phase 2: ds_read fragments (swizzled) + MFMA on current buffer.
        const unsigned short* Ab = x_lds + cur * 32768;
#pragma unroll
        for (int ks = 0; ks < 2; ++ks) {
            const int kx = ks << 5;          // ^32 shorts = flip octet bit2
            bf16x8 a[8], b[4];
#pragma unroll
            for (int fj = 0; fj < 4; ++fj)
                b[fj] = *(const bf16x8*)(
                    Ab + 16384 + ((wave_n + fj * 16 + l15) << 6) + (aoct ^ kx));
#pragma unroll
            for (int fi = 0; fi < 8; ++fi)
                a[fi] = *(const bf16x8*)(
                    Ab + ((wave_m + fi * 16 + l15) << 6) + (aoct ^ kx));

            __builtin_amdgcn_s_setprio(1);
#pragma unroll
            for (int fi = 0; fi < 8; ++fi)
#pragma unroll
                for (int fj = 0; fj < 4; ++fj)
                    acc[fi][fj] = __builtin_amdgcn_mfma_f32_16x16x32_bf16(
                        a[fi], b[fj], acc[fi][fj], 0, 0, 0);
            __builtin_amdgcn_s_setprio(0);
        }

        // One barrier per step: drains staged vmcnt + guards buffer reuse.
        __syncthreads();
    }

    // Epilogue: D row = lg*4 + reg (within 16), col = l15; add bias, store f32.
    const int nbase = h * WW + wave_n + l15;
#pragma unroll
    for (int fi = 0; fi < 8; ++fi) {
        int mrow = wave_m + fi * 16 + lg * 4;
#pragma unroll
        for (int r = 0; r < 4; ++r) {
            float bv = bias[mrow + r];
#pragma unroll
            for (int fj = 0; fj < 4; ++fj)
                out[(size_t)(mrow + r) * (HH * WW) + nbase + fj * 16] = acc[fi][fj][r] + bv;
        }
    }
}

extern "C" void kernel_launch(void* const* d_in, const int* in_sizes, int n_in,
                              void* d_out, int out_size, void* d_ws, size_t ws_size,
                              hipStream_t stream) {
    (void)in_sizes; (void)n_in; (void)out_size; (void)ws_size;
    const float* x    = (const float*)d_in[0];   // 128*256*256
    const float* w    = (const float*)d_in[1];   // 256*128*3*3
    const float* bias = (const float*)d_in[2];   // 256
    float* out = (float*)d_out;

    unsigned short* xp  = (unsigned short*)d_ws;            // bf16 [258][258][128]
    unsigned short* wpk = xp + XP_ELEMS;                    // bf16 [9][256][128]

    prep<<<dim3(2241), dim3(256), 0, stream>>>(x, w, xp, wpk);
    conv_mfma<<<dim3(256), dim3(512), 0, stream>>>(xp, wpk, bias, out);
}

// Round 5
// 129.298 us; speedup vs baseline: 1.7913x; 1.0203x over previous
//
#include <hip/hip_runtime.h>
#include <hip/hip_bf16.h>
#include <stdint.h>

// Conv2d: x[128][256][256] (f32), w[256][128][3][3] (f32), bias[256] (f32)
// out[256][256][256] (f32).  pad=1, stride=1.
// bf16 MFMA implicit GEMM: M=COUT=256, N=65536 pixels, K=9 taps x 128 ch = 1152.
//   ws: x_p bf16 [258][258][128] (padded, channel-innermost), W_pk bf16 [9][256][128].
//
// R7 (post-mortem R6: per-step 6224 cyc vs 2483 MFMA need; the 1-barrier-per-step
// __syncthreads() emits s_waitcnt vmcnt(0) -> every step drains the just-issued
// stage and convoys all 8 waves. Classic 2-phase stall, m233/m218):
//   T3+T4 port — 4 phases per K-tile (m-half x k-slice quadrant, 16 MFMA each):
//   - raw __builtin_amdgcn_s_barrier() everywhere in the loop (no implicit
//     vmcnt(0) drain).
//   - next tile's 8 staging loads issued 2-per-phase, FIFO order
//     {A0,A2,B0,B1,B2,B3,A1,A3}: the first 6 are exactly phase 0's data.
//   - counted waits, never 0 in steady state: vmcnt(2) end-of-phase-0 (this
//     tile's A1,A3 landed; next tile's 2 newest still flying) and vmcnt(2)
//     end-of-phase-3 (next tile's first 6 landed; its A1,A3 flying). Loads
//     get ~4 phases of slack instead of 0.
//   - b-fragments read once per k-slice, held in regs across the phase pair
//     -> LDS read traffic unchanged vs R6.
// Same LDS layout / XOR swizzle / staging addressing as R6 (proven).
// FP accumulation order identical -> bit-identical output expected.

#define CIN   128
#define COUT  256
#define HH    256
#define WW    256
#define HP    258
#define WP    258
#define XP_ELEMS (HP * WP * CIN)   // 8,520,192 bf16 elements

typedef __attribute__((ext_vector_type(8))) __bf16 bf16x8;
typedef __attribute__((ext_vector_type(4))) float  floatx4;
typedef __attribute__((ext_vector_type(8))) short  short8;

#define AS1 __attribute__((address_space(1)))
#define AS3 __attribute__((address_space(3)))

// ---------------- fused prep: xpose_pad | wpack | zero_border ----------------
__global__ __launch_bounds__(256) void prep(const float* __restrict__ x,
                                            const float* __restrict__ w,
                                            unsigned short* __restrict__ xp,
                                            unsigned short* __restrict__ wpk) {
    __shared__ __align__(16) unsigned short tile[64][136];  // xpose region only
    const int bid = blockIdx.x;
    const int t   = threadIdx.x;
    if (bid < 1024) {
        // transpose+cast x[c][h][w] -> x_p[h+1][w+1][c]
        int h  = bid >> 2;
        int w0 = (bid & 3) << 6;
        int wl = t & 63, icq = t >> 6;
        const float* src = x + h * WW + w0 + wl;
#pragma unroll
        for (int icb = 0; icb < 32; ++icb) {
            int ic = icb * 4 + icq;
            __hip_bfloat16 b = __float2bfloat16(src[ic * (HH * WW)]);
            tile[wl][ic] = __builtin_bit_cast(unsigned short, b);
        }
        __syncthreads();
        int wl2 = t >> 2, q = t & 3;    // 64 rows x 4 chunks of 64B
        const short8* s8 = (const short8*)&tile[wl2][q * 32];
        short8* d8 = (short8*)(xp + ((size_t)(h + 1) * WP + (w0 + 1) + wl2) * CIN + q * 32);
#pragma unroll
        for (int i = 0; i < 4; ++i) d8[i] = s8[i];
    } else if (bid < 2176) {
        // pack weights -> bf16 W_pk[kk][o][ic]
        int idx = (bid - 1024) * 256 + t;           // 0..294911
        int kk  = idx >> 15;
        int rem = idx & 32767;                      // o*128 + ic
        __hip_bfloat16 b = __float2bfloat16(w[rem * 9 + kk]);
        wpk[idx] = __builtin_bit_cast(unsigned short, b);
    } else {
        // zero the padded border: 1028 px x 16 octets, short8 stores
        int cid = (bid - 2176) * 256 + t;           // 0..16447
        if (cid < 16448) {
            int p = cid >> 4, oct = cid & 15;
            int hp, wp;
            if (p < 258)      { hp = 0;   wp = p; }
            else if (p < 516) { hp = 257; wp = p - 258; }
            else { int s = p - 516; hp = 1 + (s >> 1); wp = (s & 1) * 257; }
            short8 z = {0, 0, 0, 0, 0, 0, 0, 0};
            *(short8*)(xp + ((size_t)hp * WP + wp) * CIN + oct * 8) = z;
        }
    }
}

// ---------------- main: 256(M) x 256(pixels of row h), 8 waves, 18 K-tiles x 4 phases ----------------
// Per buffer: A[256 o][64 ch] then B[256 pix][64 ch], 16384 shorts each.
// Swizzle: physical octet = logical octet ^ (row & 7)  (octet = 16 B).
//   stage: lane writes LDS linearly; fetches pre-swizzled global octet.
//   read : frag (row, oct) at shorts row*64 + ((oct ^ (row&7))*8 ^ ks*32).
__global__ __launch_bounds__(512, 2) void conv_mfma(
    const unsigned short* __restrict__ xp,   // [258][258][128] bf16
    const unsigned short* __restrict__ wpk,  // [9][256][128]   bf16
    const float* __restrict__ bias,          // [256] f32
    float* __restrict__ out) {               // [256][65536] f32
    __shared__ __align__(16) unsigned short x_lds[2 * 32768];   // 131,072 B

    const int tid  = threadIdx.x;            // 0..511
    const int lane = tid & 63;
    const int wv   = tid >> 6;               // 0..7
    const int l15  = lane & 15;
    const int lg   = lane >> 4;              // 0..3
    const int wave_m = (wv >> 2) << 7;       // 0 or 128
    const int wave_n = (wv & 3) << 6;        // 0,64,128,192

    // XCD swizzle (bijective, 256 % 8 == 0): XCD k gets rows [k*32, k*32+32).
    const int orig = blockIdx.x;
    const int h    = ((orig & 7) << 5) | (orig >> 3);

    // Staging per-thread source offset: row-group tid>>3, pre-swizzled octet.
    const int soff = (tid >> 3) * CIN + ((((tid & 7) ^ ((tid >> 3) & 7))) << 3);
    // Per-thread swizzled read octet (shorts).
    const int aoct = (lg ^ (l15 & 7)) << 3;

    // One staging load: A_i (rows i*64..) or B_i; dests lane-contiguous 16B.
#define GLD_A(nb_, src_, i_) \
    __builtin_amdgcn_global_load_lds((const AS1 void*)((src_) + (i_) * 8192), \
        (AS3 void*)((nb_) + (i_) * 4096 + tid * 8), 16, 0, 0)
#define GLD_B(nb_, src_, i_) \
    __builtin_amdgcn_global_load_lds((const AS1 void*)((src_) + (i_) * 8192), \
        (AS3 void*)((nb_) + 16384 + (i_) * 4096 + tid * 8), 16, 0, 0)

    floatx4 acc[8][4];
#pragma unroll
    for (int fi = 0; fi < 8; ++fi)
#pragma unroll
        for (int fj = 0; fj < 4; ++fj) {
            floatx4 z = {0.f, 0.f, 0.f, 0.f};
            acc[fi][fj] = z;
        }

    // ---- prologue: stage tile 0 into buf 0 in FIFO order {A0,A2,B0..B3,A1,A3} ----
    {
        const unsigned short* a0 = wpk + soff;                       // kk=0, hf=0
        const unsigned short* b0s = xp + ((size_t)h * WP) * CIN + soff;  // kh=0, kw=0
        unsigned short* nb = x_lds;
        GLD_A(nb, a0, 0); GLD_A(nb, a0, 2);
        GLD_B(nb, b0s, 0); GLD_B(nb, b0s, 1); GLD_B(nb, b0s, 2); GLD_B(nb, b0s, 3);
        GLD_A(nb, a0, 1); GLD_A(nb, a0, 3);
    }
    asm volatile("s_waitcnt vmcnt(2)" ::: "memory");   // first 6 (phase-0 data) landed
    __builtin_amdgcn_s_barrier();

#pragma unroll
    for (int t2 = 0; t2 < 18; ++t2) {        // K-tile = (kk, ch-half)
        const int cur = t2 & 1;
        const unsigned short* Ab = x_lds + cur * 32768;
        unsigned short* nb = x_lds + (cur ^ 1) * 32768;
        const bool hn = (t2 < 17);
        const int tn  = t2 + 1;
        const int kkn = tn >> 1, hfn = tn & 1;
        const int khn = kkn / 3, kwn = kkn - khn * 3;
        const unsigned short* asrcn = wpk + (size_t)kkn * (COUT * CIN) + hfn * 64 + soff;
        const unsigned short* bsrcn = xp + ((size_t)(h + khn) * WP + kwn) * CIN + hfn * 64 + soff;

        bf16x8 b0[4], b1[4], a[4];

        // ===== phase 0: (m-half 0, ks 0) =====
#pragma unroll
        for (int fj = 0; fj < 4; ++fj)
            b0[fj] = *(const bf16x8*)(Ab + 16384 + ((wave_n + fj * 16 + l15) << 6) + aoct);
#pragma unroll
        for (int i = 0; i < 4; ++i)
            a[i] = *(const bf16x8*)(Ab + ((wave_m + i * 16 + l15) << 6) + aoct);
        if (hn) { GLD_A(nb, asrcn, 0); GLD_A(nb, asrcn, 2); }
        __builtin_amdgcn_s_barrier();
        __builtin_amdgcn_s_setprio(1);
#pragma unroll
        for (int i = 0; i < 4; ++i)
#pragma unroll
            for (int fj = 0; fj < 4; ++fj)
                acc[i][fj] = __builtin_amdgcn_mfma_f32_16x16x32_bf16(a[i], b0[fj], acc[i][fj], 0, 0, 0);
        __builtin_amdgcn_s_setprio(0);
        if (hn) asm volatile("s_waitcnt vmcnt(2)" ::: "memory");  // this tile's A1,A3 landed
        else    asm volatile("s_waitcnt vmcnt(0)" ::: "memory");
        __builtin_amdgcn_s_barrier();

        // ===== phase 1: (m-half 1, ks 0) =====
#pragma unroll
        for (int i = 0; i < 4; ++i)
            a[i] = *(const bf16x8*)(Ab + ((wave_m + 64 + i * 16 + l15) << 6) + aoct);
        if (hn) { GLD_B(nb, bsrcn, 0); GLD_B(nb, bsrcn, 1); }
        __builtin_amdgcn_s_barrier();
        __builtin_amdgcn_s_setprio(1);
#pragma unroll
        for (int i = 0; i < 4; ++i)
#pragma unroll
            for (int fj = 0; fj < 4; ++fj)
                acc[4 + i][fj] = __builtin_amdgcn_mfma_f32_16x16x32_bf16(a[i], b0[fj], acc[4 + i][fj], 0, 0, 0);
        __builtin_amdgcn_s_setprio(0);
        __builtin_amdgcn_s_barrier();

        // ===== phase 2: (m-half 0, ks 1) =====
#pragma unroll
        for (int fj = 0; fj < 4; ++fj)
            b1[fj] = *(const bf16x8*)(Ab + 16384 + ((wave_n + fj * 16 + l15) << 6) + (aoct ^ 32));
#pragma unroll
        for (int i = 0; i < 4; ++i)
            a[i] = *(const bf16x8*)(Ab + ((wave_m + i * 16 + l15) << 6) + (aoct ^ 32));
        if (hn) { GLD_B(nb, bsrcn, 2); GLD_B(nb, bsrcn, 3); }
        __builtin_amdgcn_s_barrier();
        __builtin_amdgcn_s_setprio(1);
#pragma unroll
        for (int i = 0; i < 4; ++i)
#pragma unroll
            for (int fj = 0; fj < 4; ++fj)
                acc[i][fj] = __builtin_amdgcn_mfma_f32_16x16x32_bf16(a[i], b1[fj], acc[i][fj], 0, 0, 0);
        __builtin_amdgcn_s_setprio(0);
        __builtin_amdgcn_s_barrier();

        // ===== phase 3: (m-half 1, ks 1) =====
#pragma unroll
        for (int i = 0; i < 4; ++i)
            a[i] = *(const bf16x8*)(Ab + ((wave_m + 64 + i * 16 + l15) << 6) + (aoct ^ 32));
        if (hn) { GLD_A(nb, asrcn, 1); GLD_A(nb, asrcn, 3); }
        __builtin_amdgcn_s_barrier();
        __builtin_amdgcn_s_setprio(1);
#pragma unroll
        for (int i = 0; i < 4; ++i)
#pragma unroll
            for (int fj = 0; fj < 4; ++fj)
                acc[4 + i][fj] = __builtin_amdgcn_mfma_f32_16x16x32_bf16(a[i], b1[fj], acc[4 + i][fj], 0, 0, 0);
        __builtin_amdgcn_s_setprio(0);
        if (hn) asm volatile("s_waitcnt vmcnt(2)" ::: "memory");  // next tile's first 6 landed
        __builtin_amdgcn_s_barrier();
    }
#undef GLD_A
#undef GLD_B

    // Epilogue: D row = lg*4 + reg (within 16), col = l15; add bias, store f32.
    const int nbase = h * WW + wave_n + l15;
#pragma unroll
    for (int fi = 0; fi < 8; ++fi) {
        int mrow = wave_m + fi * 16 + lg * 4;
#pragma unroll
        for (int r = 0; r < 4; ++r) {
            float bv = bias[mrow + r];
#pragma unroll
            for (int fj = 0; fj < 4; ++fj)
                out[(size_t)(mrow + r) * (HH * WW) + nbase + fj * 16] = acc[fi][fj][r] + bv;
        }
    }
}

extern "C" void kernel_launch(void* const* d_in, const int* in_sizes, int n_in,
                              void* d_out, int out_size, void* d_ws, size_t ws_size,
                              hipStream_t stream) {
    (void)in_sizes; (void)n_in; (void)out_size; (void)ws_size;
    const float* x    = (const float*)d_in[0];   // 128*256*256
    const float* w    = (const float*)d_in[1];   // 256*128*3*3
    const float* bias = (const float*)d_in[2];   // 256
    float* out = (float*)d_out;

    unsigned short* xp  = (unsigned short*)d_ws;            // bf16 [258][258][128]
    unsigned short* wpk = xp + XP_ELEMS;                    // bf16 [9][256][128]

    prep<<<dim3(2241), dim3(256), 0, stream>>>(x, w, xp, wpk);
    conv_mfma<<<dim3(256), dim3(512), 0, stream>>>(xp, wpk, bias, out);
}